// Round 1
// baseline (368.930 us; speedup 1.0000x reference)
//
#include <hip/hip_runtime.h>
#include <hip/hip_bf16.h>

typedef _Float16 f16;
typedef _Float16 f16x8 __attribute__((ext_vector_type(8)));
typedef float f32x4 __attribute__((ext_vector_type(4)));

#define NB 16
#define NN 1024
#define HH 256
#define NE 16384
#define NL 4
#define NM (NB * NN)   // 16384 rows

// ---------------- small utility kernels ----------------

__global__ void cvt_f32_f16(const float* __restrict__ s, f16* __restrict__ d, int n) {
    int i = blockIdx.x * 256 + threadIdx.x;
    if (i < n) d[i] = (f16)s[i];
}

__global__ void zero_i32(int* p, int n) {
    int i = blockIdx.x * 256 + threadIdx.x;
    if (i < n) p[i] = 0;
}

__global__ void hist_kernel(const int* __restrict__ dst, int* cnt) {
    int e = blockIdx.x * 256 + threadIdx.x;
    if (e < NE) atomicAdd(&cnt[dst[e]], 1);
}

__global__ __launch_bounds__(1024) void scan_kernel(const int* __restrict__ cnt,
                                                    int* __restrict__ offs,
                                                    int* __restrict__ cur) {
    __shared__ int s[1024];
    int i = threadIdx.x;
    int c = cnt[i];
    s[i] = c;
    __syncthreads();
    for (int ofs = 1; ofs < 1024; ofs <<= 1) {
        int v = (i >= ofs) ? s[i - ofs] : 0;
        __syncthreads();
        s[i] += v;
        __syncthreads();
    }
    offs[i + 1] = s[i];        // inclusive -> offs[i+1]
    if (i == 0) offs[0] = 0;
    cur[i] = s[i] - c;         // exclusive start = cursor init
}

__global__ void fill_kernel(const int* __restrict__ src, const int* __restrict__ dst,
                            int* cur, int* __restrict__ ssrc) {
    int e = blockIdx.x * 256 + threadIdx.x;
    if (e < NE) {
        int pos = atomicAdd(&cur[dst[e]], 1);
        ssrc[pos] = src[e];
    }
}

// ---------------- Wc = w_ih @ W[l]^T  (per layer), fp16 MFMA ----------------
// Wct[l][j][h] = sum_k w_ih[j][k] * W[l][h][k]   (j-major, h = output col)
__global__ __launch_bounds__(256) void wct_gemm(const f16* __restrict__ wih,
                                                const f16* __restrict__ wl,
                                                f16* __restrict__ wct) {
    int wid = threadIdx.x >> 6, lane = threadIdx.x & 63;
    int tile = blockIdx.x * 4 + wid;           // 4*768 tiles total
    int l = tile / 768, rem = tile % 768;
    int jt = rem / 16, ht = rem % 16;
    const f16* A = wih + (size_t)(jt * 16 + (lane & 15)) * 256 + (lane >> 4) * 8;
    const f16* B = wl + (size_t)l * 65536 + (size_t)(ht * 16 + (lane & 15)) * 256 + (lane >> 4) * 8;
    f32x4 acc;
    for (int r = 0; r < 4; ++r) acc[r] = 0.f;
    for (int k = 0; k < 256; k += 32) {
        f16x8 a = *(const f16x8*)(A + k);
        f16x8 b = *(const f16x8*)(B + k);
        acc = __builtin_amdgcn_mfma_f32_16x16x32_f16(a, b, acc, 0, 0, 0);
    }
    int col = lane & 15, row0 = (lane >> 4) * 4;
    for (int r = 0; r < 4; ++r)
        wct[(size_t)l * 196608 + (size_t)(jt * 16 + row0 + r) * 256 + ht * 16 + col] = (f16)acc[r];
}

// ---------------- per-layer: aggregate y = A*x, and x -> fp16 ----------------
// ab[row][0:256]   = fp16( sum_{e: dst=n} x[b, src[e], :] )
// ab[row][256:512] = fp16( x[row] )
__global__ __launch_bounds__(256) void agg_kernel(const float* __restrict__ x,
                                                  const int* __restrict__ offs,
                                                  const int* __restrict__ ssrc,
                                                  f16* __restrict__ ab) {
    int row = blockIdx.x;
    int b = row >> 10, n = row & 1023;
    int t = threadIdx.x;
    const float* xb = x + ((size_t)b << 18);   // b * 1024 * 256
    float s = 0.f;
    int e0 = offs[n], e1 = offs[n + 1];
    for (int p = e0; p < e1; ++p)
        s += xb[((size_t)ssrc[p] << 8) + t];
    ab[(size_t)row * 512 + t] = (f16)s;
    ab[(size_t)row * 512 + 256 + t] = (f16)x[(size_t)row * 256 + t];
}

// ---------------- fused GEMM + GRU ----------------
// For each row m, output col j in [0,256):
//   gi_{r,z,n} = y[m,:] . Wct[{j, j+256, j+512}, :] + b_ih
//   gh_{r,z,n} = xh[m,:] . whh[{j, j+256, j+512}, :] + b_hh
//   GRU elementwise -> x_dst[m][j]
__global__ __launch_bounds__(256) void gemm_gru(const f16* __restrict__ ab,
                                                const f16* __restrict__ wct,  // [768][256]
                                                const f16* __restrict__ whh,  // [768][256]
                                                const float* __restrict__ bih,
                                                const float* __restrict__ bhh,
                                                const float* __restrict__ x_src,
                                                float* __restrict__ x_dst) {
    __shared__ __align__(16) f16 As[2][64][40];
    __shared__ __align__(16) f16 Bs[6][32][40];

    int m0 = blockIdx.x * 64;
    int j0 = blockIdx.y * 32;
    int tid = threadIdx.x;
    int wid = tid >> 6, lane = tid & 63;

    f32x4 acc[6][2];
#pragma unroll
    for (int g = 0; g < 6; ++g)
#pragma unroll
        for (int jt = 0; jt < 2; ++jt)
#pragma unroll
            for (int r = 0; r < 4; ++r) acc[g][jt][r] = 0.f;

    int ar = tid >> 2, ac = (tid & 3) * 8;

    for (int kk = 0; kk < 256; kk += 32) {
        // stage A (both halves)
        f16x8 a0 = *(const f16x8*)(ab + (size_t)(m0 + ar) * 512 + kk + ac);
        f16x8 a1 = *(const f16x8*)(ab + (size_t)(m0 + ar) * 512 + 256 + kk + ac);
        *(f16x8*)(&As[0][ar][ac]) = a0;
        *(f16x8*)(&As[1][ar][ac]) = a1;
        // stage B: 6 tiles x 32 rows x 4 chunks = 768 chunks, 3 per thread
#pragma unroll
        for (int i = 0; i < 3; ++i) {
            int idx = tid + i * 256;
            int g = idx >> 7;
            int r = (idx >> 2) & 31;
            int c = (idx & 3) * 8;
            const f16* src = (g < 3)
                ? (wct + (size_t)(j0 + g * 256 + r) * 256 + kk + c)
                : (whh + (size_t)(j0 + (g - 3) * 256 + r) * 256 + kk + c);
            *(f16x8*)(&Bs[g][r][c]) = *(const f16x8*)src;
        }
        __syncthreads();

        int fr = lane & 15, fo = (lane >> 4) * 8;
        f16x8 aF[2];
        aF[0] = *(const f16x8*)(&As[0][wid * 16 + fr][fo]);
        aF[1] = *(const f16x8*)(&As[1][wid * 16 + fr][fo]);
#pragma unroll
        for (int g = 0; g < 6; ++g) {
#pragma unroll
            for (int jt = 0; jt < 2; ++jt) {
                f16x8 bF = *(const f16x8*)(&Bs[g][jt * 16 + fr][fo]);
                acc[g][jt] = __builtin_amdgcn_mfma_f32_16x16x32_f16(
                    (g < 3) ? aF[0] : aF[1], bF, acc[g][jt], 0, 0, 0);
            }
        }
        __syncthreads();
    }

    // epilogue: GRU
    int fr = lane & 15, frow = (lane >> 4) * 4;
#pragma unroll
    for (int jt = 0; jt < 2; ++jt) {
        int j = j0 + jt * 16 + fr;
        float bir = bih[j], biz = bih[j + 256], bin = bih[j + 512];
        float bhr = bhh[j], bhz = bhh[j + 256], bhn = bhh[j + 512];
#pragma unroll
        for (int r = 0; r < 4; ++r) {
            int row = m0 + wid * 16 + frow + r;
            float gir = acc[0][jt][r] + bir;
            float giz = acc[1][jt][r] + biz;
            float gin = acc[2][jt][r] + bin;
            float ghr = acc[3][jt][r] + bhr;
            float ghz = acc[4][jt][r] + bhz;
            float ghn = acc[5][jt][r] + bhn;
            float rg = 1.f / (1.f + __expf(-(gir + ghr)));
            float zg = 1.f / (1.f + __expf(-(giz + ghz)));
            float ng = tanhf(gin + rg * ghn);
            float h = x_src[(size_t)row * 256 + j];
            x_dst[(size_t)row * 256 + j] = (1.f - zg) * ng + zg * h;
        }
    }
}

// ---------------- launch ----------------

extern "C" void kernel_launch(void* const* d_in, const int* in_sizes, int n_in,
                              void* d_out, int out_size, void* d_ws, size_t ws_size,
                              hipStream_t stream) {
    const float* emb = (const float*)d_in[0];
    const int* eidx = (const int*)d_in[1];   // [2][E]: row0 = src, row1 = dst
    const float* W = (const float*)d_in[2];  // [4][256][256] (h, k)
    const float* wih = (const float*)d_in[3];
    const float* whh = (const float*)d_in[4];
    const float* bih = (const float*)d_in[5];
    const float* bhh = (const float*)d_in[6];
    float* out = (float*)d_out;

    char* ws = (char*)d_ws;
    f16* ab = (f16*)ws;                                 // 16 MB
    f16* wct = (f16*)(ws + (size_t)16 * 1024 * 1024);   // 4*768*256
    f16* whh_h = wct + (size_t)4 * 768 * 256;           // 768*256
    f16* wih_h = whh_h + (size_t)768 * 256;             // 768*256
    f16* w_h = wih_h + (size_t)768 * 256;               // 4*256*256
    int* cnt = (int*)(w_h + (size_t)4 * 256 * 256);     // 1024
    int* offs = cnt + 1024;                             // 1025 (+pad)
    int* cur = offs + 1056;                             // 1024
    int* ssrc = cur + 1024;                             // 16384

    // weight conversions
    cvt_f32_f16<<<(768 * 256 + 255) / 256, 256, 0, stream>>>(wih, wih_h, 768 * 256);
    cvt_f32_f16<<<(768 * 256 + 255) / 256, 256, 0, stream>>>(whh, whh_h, 768 * 256);
    cvt_f32_f16<<<(4 * 256 * 256 + 255) / 256, 256, 0, stream>>>(W, w_h, 4 * 256 * 256);

    // CSR build (edges bucketed by dst)
    zero_i32<<<4, 256, 0, stream>>>(cnt, 1024);
    hist_kernel<<<64, 256, 0, stream>>>(eidx + NE, cnt);
    scan_kernel<<<1, 1024, 0, stream>>>(cnt, offs, cur);
    fill_kernel<<<64, 256, 0, stream>>>(eidx, eidx + NE, cur, ssrc);

    // Wc precompute
    wct_gemm<<<768, 256, 0, stream>>>(wih_h, w_h, wct);

    const float* xs = emb;
    for (int l = 0; l < NL; ++l) {
        agg_kernel<<<NM, 256, 0, stream>>>(xs, offs, ssrc, ab);
        gemm_gru<<<dim3(NM / 64, 8), 256, 0, stream>>>(
            ab, wct + (size_t)l * 768 * 256, whh_h, bih, bhh, xs, out);
        xs = out;
    }
}

// Round 2
// 262.900 us; speedup vs baseline: 1.4033x; 1.4033x over previous
//
#include <hip/hip_runtime.h>
#include <hip/hip_bf16.h>

typedef _Float16 f16;
typedef _Float16 f16x4 __attribute__((ext_vector_type(4)));
typedef _Float16 f16x8 __attribute__((ext_vector_type(8)));
typedef float f32x4 __attribute__((ext_vector_type(4)));

#define NB 16
#define NN 1024
#define HH 256
#define NE 16384
#define NL 4
#define NM (NB * NN)   // 16384 rows

// ---------------- small utility kernels ----------------

__global__ void cvt_f32_f16(const float* __restrict__ s, f16* __restrict__ d, int n) {
    int i = blockIdx.x * 256 + threadIdx.x;
    if (i < n) d[i] = (f16)s[i];
}

// vectorized: 8 elements / thread
__global__ void cvt_f32_f16v(const float* __restrict__ s, f16* __restrict__ d, int n8) {
    int i = blockIdx.x * 256 + threadIdx.x;
    if (i < n8) {
        const float4* p = (const float4*)(s + (size_t)i * 8);
        float4 a = p[0], b = p[1];
        f16x8 v;
        v[0] = (f16)a.x; v[1] = (f16)a.y; v[2] = (f16)a.z; v[3] = (f16)a.w;
        v[4] = (f16)b.x; v[5] = (f16)b.y; v[6] = (f16)b.z; v[7] = (f16)b.w;
        *(f16x8*)(d + (size_t)i * 8) = v;
    }
}

__global__ void zero_i32(int* p, int n) {
    int i = blockIdx.x * 256 + threadIdx.x;
    if (i < n) p[i] = 0;
}

__global__ void hist_kernel(const int* __restrict__ dst, int* cnt) {
    int e = blockIdx.x * 256 + threadIdx.x;
    if (e < NE) atomicAdd(&cnt[dst[e]], 1);
}

__global__ __launch_bounds__(1024) void scan_kernel(const int* __restrict__ cnt,
                                                    int* __restrict__ offs,
                                                    int* __restrict__ cur) {
    __shared__ int s[1024];
    int i = threadIdx.x;
    int c = cnt[i];
    s[i] = c;
    __syncthreads();
    for (int ofs = 1; ofs < 1024; ofs <<= 1) {
        int v = (i >= ofs) ? s[i - ofs] : 0;
        __syncthreads();
        s[i] += v;
        __syncthreads();
    }
    offs[i + 1] = s[i];
    if (i == 0) offs[0] = 0;
    cur[i] = s[i] - c;
}

__global__ void fill_kernel(const int* __restrict__ src, const int* __restrict__ dst,
                            int* cur, int* __restrict__ ssrc) {
    int e = blockIdx.x * 256 + threadIdx.x;
    if (e < NE) {
        int pos = atomicAdd(&cur[dst[e]], 1);
        ssrc[pos] = src[e];
    }
}

// ---------------- Wc = w_ih @ W[l]^T  (per layer), fp16 MFMA ----------------
__global__ __launch_bounds__(256) void wct_gemm(const f16* __restrict__ wih,
                                                const f16* __restrict__ wl,
                                                f16* __restrict__ wct) {
    int wid = threadIdx.x >> 6, lane = threadIdx.x & 63;
    int tile = blockIdx.x * 4 + wid;
    int l = tile / 768, rem = tile % 768;
    int jt = rem / 16, ht = rem % 16;
    const f16* A = wih + (size_t)(jt * 16 + (lane & 15)) * 256 + (lane >> 4) * 8;
    const f16* B = wl + (size_t)l * 65536 + (size_t)(ht * 16 + (lane & 15)) * 256 + (lane >> 4) * 8;
    f32x4 acc;
    for (int r = 0; r < 4; ++r) acc[r] = 0.f;
    for (int k = 0; k < 256; k += 32) {
        f16x8 a = *(const f16x8*)(A + k);
        f16x8 b = *(const f16x8*)(B + k);
        acc = __builtin_amdgcn_mfma_f32_16x16x32_f16(a, b, acc, 0, 0, 0);
    }
    int col = lane & 15, row0 = (lane >> 4) * 4;
    for (int r = 0; r < 4; ++r)
        wct[(size_t)l * 196608 + (size_t)(jt * 16 + row0 + r) * 256 + ht * 16 + col] = (f16)acc[r];
}

// ---------------- aggregation: y[row] = sum over incoming edges ----------------
// F16 path: gather from fp16 xh, ab stride 256 (y only).
// fp32 path: gather from fp32 x, ab stride 512 (y | fp16(x)).
template<bool F16>
__global__ __launch_bounds__(256) void agg_kernel(const void* __restrict__ xsrc,
                                                  const int* __restrict__ offs,
                                                  const int* __restrict__ ssrc,
                                                  f16* __restrict__ ab) {
    int row = blockIdx.x * 4 + (threadIdx.x >> 6);
    int lane = threadIdx.x & 63;
    int b = row >> 10, n = row & 1023;
    int e0 = offs[n], e1 = offs[n + 1];
    float s0 = 0.f, s1 = 0.f, s2 = 0.f, s3 = 0.f;
    if constexpr (F16) {
        const f16* xb = (const f16*)xsrc + ((size_t)b << 18);
        int p = e0;
        for (; p + 1 < e1; p += 2) {
            int i0 = ssrc[p], i1 = ssrc[p + 1];
            f16x4 v0 = *(const f16x4*)(xb + (((size_t)i0) << 8) + lane * 4);
            f16x4 v1 = *(const f16x4*)(xb + (((size_t)i1) << 8) + lane * 4);
            s0 += (float)v0[0] + (float)v1[0];
            s1 += (float)v0[1] + (float)v1[1];
            s2 += (float)v0[2] + (float)v1[2];
            s3 += (float)v0[3] + (float)v1[3];
        }
        if (p < e1) {
            f16x4 v0 = *(const f16x4*)(xb + (((size_t)ssrc[p]) << 8) + lane * 4);
            s0 += (float)v0[0]; s1 += (float)v0[1]; s2 += (float)v0[2]; s3 += (float)v0[3];
        }
        f16x4 o; o[0] = (f16)s0; o[1] = (f16)s1; o[2] = (f16)s2; o[3] = (f16)s3;
        *(f16x4*)(ab + (size_t)row * 256 + lane * 4) = o;
    } else {
        const float* xb = (const float*)xsrc + ((size_t)b << 18);
        for (int p = e0; p < e1; ++p) {
            float4 v = *(const float4*)(xb + (((size_t)ssrc[p]) << 8) + lane * 4);
            s0 += v.x; s1 += v.y; s2 += v.z; s3 += v.w;
        }
        f16x4 o; o[0] = (f16)s0; o[1] = (f16)s1; o[2] = (f16)s2; o[3] = (f16)s3;
        *(f16x4*)(ab + (size_t)row * 512 + lane * 4) = o;
        float4 v = *(const float4*)((const float*)xsrc + (size_t)row * 256 + lane * 4);
        f16x4 o2; o2[0] = (f16)v.x; o2[1] = (f16)v.y; o2[2] = (f16)v.z; o2[3] = (f16)v.w;
        *(f16x4*)(ab + (size_t)row * 512 + 256 + lane * 4) = o2;
    }
}

// ---------------- fused GEMM + GRU ----------------
template<bool F16>
__global__ __launch_bounds__(256) void gemm_gru(const f16* __restrict__ ab,
                                                const f16* __restrict__ xh_src,
                                                const f16* __restrict__ wct,
                                                const f16* __restrict__ whh,
                                                const float* __restrict__ bih,
                                                const float* __restrict__ bhh,
                                                const float* __restrict__ x_src,
                                                float* __restrict__ out,
                                                f16* __restrict__ xh_dst,
                                                int wout, int wxh) {
    __shared__ __align__(16) f16 As[2][64][40];
    __shared__ __align__(16) f16 Bs[6][32][40];

    constexpr int SA = F16 ? 256 : 512;
    int m0 = blockIdx.x * 64;
    int j0 = blockIdx.y * 32;
    int tid = threadIdx.x;
    int wid = tid >> 6, lane = tid & 63;

    f32x4 acc[6][2];
#pragma unroll
    for (int g = 0; g < 6; ++g)
#pragma unroll
        for (int jt = 0; jt < 2; ++jt)
#pragma unroll
            for (int r = 0; r < 4; ++r) acc[g][jt][r] = 0.f;

    int ar = tid >> 2, ac = (tid & 3) * 8;

    for (int kk = 0; kk < 256; kk += 32) {
        f16x8 a0 = *(const f16x8*)(ab + (size_t)(m0 + ar) * SA + kk + ac);
        const f16* xrow;
        if constexpr (F16) xrow = xh_src + (size_t)(m0 + ar) * 256;
        else               xrow = ab + (size_t)(m0 + ar) * 512 + 256;
        f16x8 a1 = *(const f16x8*)(xrow + kk + ac);
        *(f16x8*)(&As[0][ar][ac]) = a0;
        *(f16x8*)(&As[1][ar][ac]) = a1;
#pragma unroll
        for (int i = 0; i < 3; ++i) {
            int idx = tid + i * 256;
            int g = idx >> 7;
            int r = (idx >> 2) & 31;
            int c = (idx & 3) * 8;
            const f16* src = (g < 3)
                ? (wct + (size_t)(j0 + g * 256 + r) * 256 + kk + c)
                : (whh + (size_t)(j0 + (g - 3) * 256 + r) * 256 + kk + c);
            *(f16x8*)(&Bs[g][r][c]) = *(const f16x8*)src;
        }
        __syncthreads();

        int fr = lane & 15, fo = (lane >> 4) * 8;
        f16x8 aF[2];
        aF[0] = *(const f16x8*)(&As[0][wid * 16 + fr][fo]);
        aF[1] = *(const f16x8*)(&As[1][wid * 16 + fr][fo]);
#pragma unroll
        for (int g = 0; g < 6; ++g) {
#pragma unroll
            for (int jt = 0; jt < 2; ++jt) {
                f16x8 bF = *(const f16x8*)(&Bs[g][jt * 16 + fr][fo]);
                acc[g][jt] = __builtin_amdgcn_mfma_f32_16x16x32_f16(
                    (g < 3) ? aF[0] : aF[1], bF, acc[g][jt], 0, 0, 0);
            }
        }
        __syncthreads();
    }

    int fr = lane & 15, frow = (lane >> 4) * 4;
#pragma unroll
    for (int jt = 0; jt < 2; ++jt) {
        int j = j0 + jt * 16 + fr;
        float bir = bih[j], biz = bih[j + 256], bin = bih[j + 512];
        float bhr = bhh[j], bhz = bhh[j + 256], bhn = bhh[j + 512];
#pragma unroll
        for (int r = 0; r < 4; ++r) {
            int row = m0 + wid * 16 + frow + r;
            float gir = acc[0][jt][r] + bir;
            float giz = acc[1][jt][r] + biz;
            float gin = acc[2][jt][r] + bin;
            float ghr = acc[3][jt][r] + bhr;
            float ghz = acc[4][jt][r] + bhz;
            float ghn = acc[5][jt][r] + bhn;
            float rg = 1.f / (1.f + __expf(-(gir + ghr)));
            float zg = 1.f / (1.f + __expf(-(giz + ghz)));
            float ng = tanhf(gin + rg * ghn);
            float h;
            if constexpr (F16) h = (float)xh_src[(size_t)row * 256 + j];
            else               h = x_src[(size_t)row * 256 + j];
            float res = (1.f - zg) * ng + zg * h;
            if (wout) out[(size_t)row * 256 + j] = res;
            if constexpr (F16) {
                if (wxh) xh_dst[(size_t)row * 256 + j] = (f16)res;
            }
        }
    }
}

// ---------------- launch ----------------

extern "C" void kernel_launch(void* const* d_in, const int* in_sizes, int n_in,
                              void* d_out, int out_size, void* d_ws, size_t ws_size,
                              hipStream_t stream) {
    const float* emb = (const float*)d_in[0];
    const int* eidx = (const int*)d_in[1];
    const float* W = (const float*)d_in[2];
    const float* wih = (const float*)d_in[3];
    const float* whh = (const float*)d_in[4];
    const float* bih = (const float*)d_in[5];
    const float* bhh = (const float*)d_in[6];
    float* out = (float*)d_out;

    // fast-path layout (needs ~26.9 MB)
    const size_t NEL = (size_t)NM * 256;            // 4,194,304
    f16* ab = (f16*)d_ws;
    f16* xhA = ab + NEL;
    f16* xhB = xhA + NEL;
    f16* wct_f = xhB + NEL;
    const size_t need = ((size_t)3 * NEL + 786432 + 196608 + 196608 + 262144) * 2 + 80000;
    bool fast = ws_size >= need;

    f16 *wct, *whh_h, *wih_h, *w_h;
    if (fast) {
        wct = wct_f;
    } else {
        wct = (f16*)((char*)d_ws + (size_t)16 * 1024 * 1024);   // r1 layout, ab stride 512
    }
    whh_h = wct + (size_t)4 * 768 * 256;
    wih_h = whh_h + (size_t)768 * 256;
    w_h = wih_h + (size_t)768 * 256;
    int* cnt = (int*)(w_h + (size_t)4 * 256 * 256);
    int* offs = cnt + 1024;
    int* cur = offs + 1056;
    int* ssrc = cur + 1024;

    cvt_f32_f16<<<(768 * 256 + 255) / 256, 256, 0, stream>>>(wih, wih_h, 768 * 256);
    cvt_f32_f16<<<(768 * 256 + 255) / 256, 256, 0, stream>>>(whh, whh_h, 768 * 256);
    cvt_f32_f16<<<(4 * 256 * 256 + 255) / 256, 256, 0, stream>>>(W, w_h, 4 * 256 * 256);

    zero_i32<<<4, 256, 0, stream>>>(cnt, 1024);
    hist_kernel<<<64, 256, 0, stream>>>(eidx + NE, cnt);
    scan_kernel<<<1, 1024, 0, stream>>>(cnt, offs, cur);
    fill_kernel<<<64, 256, 0, stream>>>(eidx, eidx + NE, cur, ssrc);

    wct_gemm<<<768, 256, 0, stream>>>(wih_h, w_h, wct);

    if (fast) {
        cvt_f32_f16v<<<(int)(NEL / 8 + 255) / 256, 256, 0, stream>>>(emb, xhA, (int)(NEL / 8));
        for (int l = 0; l < NL; ++l) {
            f16* xs = (l & 1) ? xhB : xhA;
            f16* xd = (l & 1) ? xhA : xhB;
            agg_kernel<true><<<NM / 4, 256, 0, stream>>>(xs, offs, ssrc, ab);
            gemm_gru<true><<<dim3(NM / 64, 8), 256, 0, stream>>>(
                ab, xs, wct + (size_t)l * 768 * 256, whh_h, bih, bhh,
                nullptr, out, xd, (l == NL - 1) ? 1 : 0, (l < NL - 1) ? 1 : 0);
        }
    } else {
        const float* xs = emb;
        for (int l = 0; l < NL; ++l) {
            agg_kernel<false><<<NM / 4, 256, 0, stream>>>(xs, offs, ssrc, ab);
            gemm_gru<false><<<dim3(NM / 64, 8), 256, 0, stream>>>(
                ab, nullptr, wct + (size_t)l * 768 * 256, whh_h, bih, bhh,
                xs, out, nullptr, 1, 0);
            xs = out;
        }
    }
}